// Round 1
// baseline (1592.060 us; speedup 1.0000x reference)
//
#include <hip/hip_runtime.h>
#include <hip/hip_bf16.h>

typedef __bf16 bf16;
typedef bf16 bf16x8 __attribute__((ext_vector_type(8)));
typedef float f32x4 __attribute__((ext_vector_type(4)));

#define Bsz 512
#define Ssz 199
#define Dsz 128
#define GR 16
#define NBLK (Bsz / GR)

__device__ __forceinline__ float sigmoidf_(float x) { return 1.f / (1.f + __expf(-x)); }
__device__ __forceinline__ float tanhf_(float x) {
  float xc = fminf(fmaxf(x, -15.f), 15.f);
  float e = __expf(2.f * xc);
  return (e - 1.f) / (e + 1.f);
}

__device__ __forceinline__ f32x4 mfma16(bf16x8 a, bf16x8 b, f32x4 c) {
  return __builtin_amdgcn_mfma_f32_16x16x32_bf16(a, b, c, 0, 0, 0);
}

// ---------------- K1: last-seen time tables ----------------
__global__ void k_lastseen(const int* __restrict__ np_, const int* __restrict__ ns_,
                           int* __restrict__ lpt, int* __restrict__ lst) {
  __shared__ unsigned short tabP[20000];
  __shared__ unsigned short tabS[500];
  __shared__ int pbuf[Ssz], sbuf[Ssz];
  int b = blockIdx.x;
  for (int i = threadIdx.x; i < 20000; i += blockDim.x) tabP[i] = 0;
  for (int i = threadIdx.x; i < 500; i += blockDim.x) tabS[i] = 0;
  for (int i = threadIdx.x; i < Ssz; i += blockDim.x) {
    pbuf[i] = np_[b * Ssz + i];
    sbuf[i] = ns_[b * Ssz + i];
  }
  __syncthreads();
  if (threadIdx.x == 0) {
    for (int t = 0; t < Ssz; ++t) {
      int p = pbuf[t], s = sbuf[t];
      lpt[b * Ssz + t] = tabP[p]; tabP[p] = (unsigned short)t;
      lst[b * Ssz + t] = tabS[s]; tabS[s] = (unsigned short)t;
    }
  }
}

// ---------------- K2: pack weights into MFMA B-fragment layout ----------------
// dst frag g=(nt,ks,lane): 8 contiguous bf16 = W[ks*32+(l>>4)*8+j][nt*16+(l&15)]
__global__ void k_pack(const float* __restrict__ W, bf16* __restrict__ dst, int K) {
  int g = blockIdx.x * blockDim.x + threadIdx.x;
  int KS = K / 32;
  int total = 8 * KS * 64;
  if (g >= total) return;
  int l = g & 63;
  int ks = (g >> 6) % KS;
  int nt = (g >> 6) / KS;
  int col = nt * 16 + (l & 15);
  int k0 = ks * 32 + (l >> 4) * 8;
  bf16x8 v;
  for (int j = 0; j < 8; ++j) v[j] = (bf16)W[(size_t)(k0 + j) * 128 + col];
  *(bf16x8*)&dst[(size_t)g * 8] = v;
}

// ---------------- K3: time-embedding projections (with bias folded) ----------------
// dst[d][n] = bias[n] + sum_k TE[d][k] * W[(128+k)][n]
__global__ void k_tge(const float* __restrict__ TE, const float* __restrict__ W,
                      const float* __restrict__ bias, float* __restrict__ dst) {
  __shared__ float te[128];
  int d = blockIdx.x, n = threadIdx.x;
  te[n] = TE[d * 128 + n];
  __syncthreads();
  float acc = bias[n];
  for (int k = 0; k < 128; ++k) acc += te[k] * W[(size_t)(128 + k) * 128 + n];
  dst[d * 128 + n] = acc;
}

// ---------------- main recurrent kernel ----------------
struct MainParams {
  const int *next_problem, *next_skill, *next_ans;
  const float *pro_embed, *skill_embed, *ans_embed;
  const float *akt_pro_diff, *akt_pro_change;
  const float *ls_state, *pro_state0, *skill_state0;
  const int *lpt, *lst;
  const float *TGEp, *TGEs, *cAF;
  const bf16 *PWpf, *PWsf, *PWaf, *PWps, *PWss, *PWas, *PWo1;
  const float *b_ps, *b_ss, *b_as, *b_o1, *W_o2, *b_o2;
  bf16 *proSt, *skSt;
  float *out;
};

__global__ void __launch_bounds__(256, 1) k_main(MainParams P) {
  const int b0 = blockIdx.x * GR;
  const int tid = threadIdx.x;
  const int lane = tid & 63;
  const int wv = tid >> 6;
  const int r16 = tid >> 4;          // 0..15: row for gather ops
  const int c8 = (tid & 15) * 8;     // col group for gather ops

  __shared__ __align__(16) bf16 Ala[16][136];
  __shared__ __align__(16) bf16 Albp[16][136];
  __shared__ __align__(16) bf16 Albs[16][136];
  __shared__ __align__(16) bf16 AnX[16][136];
  __shared__ __align__(16) bf16 Anpe[16][136];
  __shared__ __align__(16) float GPp[16][128];
  __shared__ __align__(16) float GPs[16][128];
  __shared__ __align__(16) float Hh[16][128];
  __shared__ __align__(16) bf16 STG[2][16][128];
  __shared__ float bps[128], bss[128], bas[128], bo1[128], caf[128], w2[128];
  __shared__ int lptS[16], lstS[16];

  if (tid < 128) {
    bps[tid] = P.b_ps[tid];
    bss[tid] = P.b_ss[tid];
    bas[tid] = P.b_as[tid];
    bo1[tid] = P.b_o1[tid];
    caf[tid] = P.cAF[tid];
    w2[tid]  = P.W_o2[tid];
  }
  // Ala <- ls_state broadcast; init state slot 0 with row 0 of the inits
  {
    bf16x8 va, vp, vs;
    for (int j = 0; j < 8; ++j) {
      va[j] = (bf16)P.ls_state[c8 + j];
      vp[j] = (bf16)P.pro_state0[c8 + j];
      vs[j] = (bf16)P.skill_state0[c8 + j];
    }
    *(bf16x8*)&Ala[r16][c8] = va;
    *(bf16x8*)&P.proSt[((size_t)(b0 + r16) * Ssz) * Dsz + c8] = vp;
    *(bf16x8*)&P.skSt[((size_t)(b0 + r16) * Ssz) * Dsz + c8] = vs;
  }
  if (tid < 16) lptS[tid] = P.lpt[(b0 + tid) * Ssz];
  else if (tid < 32) lstS[tid - 16] = P.lst[(b0 + tid - 16) * Ssz];
  __syncthreads();

  auto gatherState = [&](int t) {
    int lp = lptS[r16], lsv = lstS[r16];
    *(bf16x8*)&Albp[r16][c8] =
        *(const bf16x8*)&P.proSt[((size_t)(b0 + r16) * Ssz + lp) * Dsz + c8];
    *(bf16x8*)&Albs[r16][c8] =
        *(const bf16x8*)&P.skSt[((size_t)(b0 + r16) * Ssz + lsv) * Dsz + c8];
    float4 gp0 = *(const float4*)&P.TGEp[(size_t)(t - lp) * Dsz + c8];
    float4 gp1 = *(const float4*)&P.TGEp[(size_t)(t - lp) * Dsz + c8 + 4];
    float4 gs0 = *(const float4*)&P.TGEs[(size_t)(t - lsv) * Dsz + c8];
    float4 gs1 = *(const float4*)&P.TGEs[(size_t)(t - lsv) * Dsz + c8 + 4];
    *(float4*)&GPp[r16][c8] = gp0; *(float4*)&GPp[r16][c8 + 4] = gp1;
    *(float4*)&GPs[r16][c8] = gs0; *(float4*)&GPs[r16][c8 + 4] = gs1;
  };
  auto gatherNX = [&](int t) {
    int idx = (b0 + r16) * Ssz + t;
    int np = P.next_problem[idx], ns = P.next_skill[idx], na = P.next_ans[idx];
    float diff = P.akt_pro_diff[np];
    const float* pe = &P.pro_embed[(size_t)np * Dsz + c8];
    const float* se = &P.skill_embed[(size_t)ns * Dsz + c8];
    const float* ch = &P.akt_pro_change[(size_t)ns * Dsz + c8];
    const float* ae = &P.ans_embed[(size_t)na * Dsz + c8];
    bf16x8 vn, vx;
    for (int j = 0; j < 8; ++j) {
      float npv = pe[j] + se[j] + diff * ch[j];
      vn[j] = (bf16)npv;
      vx[j] = (bf16)(npv + ae[j]);
    }
    *(bf16x8*)&Anpe[r16][c8] = vn;
    *(bf16x8*)&AnX[r16][c8] = vx;
  };

  // t = 0 gathers
  gatherState(0);
  gatherNX(0);
  __syncthreads();

  const int arow = lane & 15;
  const int apos = (lane >> 4) * 8;
  auto ldA = [&](const bf16 (*T)[136], int ks) {
    return *(const bf16x8*)&T[arow][ks * 32 + apos];
  };
  auto ldB = [&](const bf16* PW, int KS, int nt, int ks) {
    return *(const bf16x8*)&PW[(size_t)((nt * KS + ks) * 64 + lane) * 8];
  };

  const int nt0 = wv, nt1 = wv + 4;
  const int rb = (lane >> 4) * 4;
  const int cA = nt0 * 16 + (lane & 15);
  const int cB = nt1 * 16 + (lane & 15);
  const float bo2 = P.b_o2[0];

  for (int t = 0; t < Ssz; ++t) {
    // ---- Phase B: gate matmuls (state @ W_top), K=128
    f32x4 dpf0{}, dpf1{}, dsf0{}, dsf1{}, daf0{}, daf1{};
    for (int ks = 0; ks < 4; ++ks) {
      bf16x8 ap = ldA(Albp, ks), av = ldA(Albs, ks), aa = ldA(Ala, ks);
      dpf0 = mfma16(ap, ldB(P.PWpf, 4, nt0, ks), dpf0);
      dpf1 = mfma16(ap, ldB(P.PWpf, 4, nt1, ks), dpf1);
      dsf0 = mfma16(av, ldB(P.PWsf, 4, nt0, ks), dsf0);
      dsf1 = mfma16(av, ldB(P.PWsf, 4, nt1, ks), dsf1);
      daf0 = mfma16(aa, ldB(P.PWaf, 4, nt0, ks), daf0);
      daf1 = mfma16(aa, ldB(P.PWaf, 4, nt1, ks), daf1);
    }
    __syncthreads();
    // ---- Phase C: gate epilogue (sigmoid, multiply, write gated states in place)
    for (int r = 0; r < 4; ++r) {
      int row = rb + r;
      float g;
      g = sigmoidf_(dpf0[r] + GPp[row][cA]); Albp[row][cA] = (bf16)((float)Albp[row][cA] * g);
      g = sigmoidf_(dpf1[r] + GPp[row][cB]); Albp[row][cB] = (bf16)((float)Albp[row][cB] * g);
      g = sigmoidf_(dsf0[r] + GPs[row][cA]); Albs[row][cA] = (bf16)((float)Albs[row][cA] * g);
      g = sigmoidf_(dsf1[r] + GPs[row][cB]); Albs[row][cB] = (bf16)((float)Albs[row][cB] * g);
      g = sigmoidf_(daf0[r] + caf[cA]);      Ala[row][cA]  = (bf16)((float)Ala[row][cA] * g);
      g = sigmoidf_(daf1[r] + caf[cB]);      Ala[row][cB]  = (bf16)((float)Ala[row][cB] * g);
    }
    __syncthreads();
    // ---- Phase D: update matmuls ([state|nX] @ W, K=256) + head (K=512)
    f32x4 uas0{}, uas1{}, ups0{}, ups1{}, uss0{}, uss1{};
    for (int ks = 0; ks < 4; ++ks) {
      bf16x8 aa = ldA(Ala, ks), ap = ldA(Albp, ks), av = ldA(Albs, ks), ax = ldA(AnX, ks);
      uas0 = mfma16(aa, ldB(P.PWas, 8, nt0, ks), uas0);
      uas1 = mfma16(aa, ldB(P.PWas, 8, nt1, ks), uas1);
      uas0 = mfma16(ax, ldB(P.PWas, 8, nt0, ks + 4), uas0);
      uas1 = mfma16(ax, ldB(P.PWas, 8, nt1, ks + 4), uas1);
      ups0 = mfma16(ap, ldB(P.PWps, 8, nt0, ks), ups0);
      ups1 = mfma16(ap, ldB(P.PWps, 8, nt1, ks), ups1);
      ups0 = mfma16(ax, ldB(P.PWps, 8, nt0, ks + 4), ups0);
      ups1 = mfma16(ax, ldB(P.PWps, 8, nt1, ks + 4), ups1);
      uss0 = mfma16(av, ldB(P.PWss, 8, nt0, ks), uss0);
      uss1 = mfma16(av, ldB(P.PWss, 8, nt1, ks), uss1);
      uss0 = mfma16(ax, ldB(P.PWss, 8, nt0, ks + 4), uss0);
      uss1 = mfma16(ax, ldB(P.PWss, 8, nt1, ks + 4), uss1);
    }
    f32x4 h0{}, h1{};
    for (int ks = 0; ks < 4; ++ks) {
      bf16x8 aa = ldA(Ala, ks), ap = ldA(Albp, ks), av = ldA(Albs, ks), an = ldA(Anpe, ks);
      h0 = mfma16(aa, ldB(P.PWo1, 16, nt0, ks), h0);
      h1 = mfma16(aa, ldB(P.PWo1, 16, nt1, ks), h1);
      h0 = mfma16(ap, ldB(P.PWo1, 16, nt0, ks + 4), h0);
      h1 = mfma16(ap, ldB(P.PWo1, 16, nt1, ks + 4), h1);
      h0 = mfma16(av, ldB(P.PWo1, 16, nt0, ks + 8), h0);
      h1 = mfma16(av, ldB(P.PWo1, 16, nt1, ks + 8), h1);
      h0 = mfma16(an, ldB(P.PWo1, 16, nt0, ks + 12), h0);
      h1 = mfma16(an, ldB(P.PWo1, 16, nt1, ks + 12), h1);
    }
    __syncthreads();
    // ---- Phase E: epilogues (tanh updates, relu head)
    for (int r = 0; r < 4; ++r) {
      int row = rb + r;
      {
        float lav  = (float)Ala[row][cA];
        float lbpv = (float)Albp[row][cA];
        float lbsv = (float)Albs[row][cA];
        Ala[row][cA]    = (bf16)(lav  + tanhf_(uas0[r] + bas[cA]));
        STG[0][row][cA] = (bf16)(lbpv + tanhf_(ups0[r] + bps[cA]));
        STG[1][row][cA] = (bf16)(lbsv + tanhf_(uss0[r] + bss[cA]));
        Hh[row][cA] = fmaxf(h0[r] + bo1[cA], 0.f);
      }
      {
        float lav  = (float)Ala[row][cB];
        float lbpv = (float)Albp[row][cB];
        float lbsv = (float)Albs[row][cB];
        Ala[row][cB]    = (bf16)(lav  + tanhf_(uas1[r] + bas[cB]));
        STG[0][row][cB] = (bf16)(lbpv + tanhf_(ups1[r] + bps[cB]));
        STG[1][row][cB] = (bf16)(lbsv + tanhf_(uss1[r] + bss[cB]));
        Hh[row][cB] = fmaxf(h1[r] + bo1[cB], 0.f);
      }
    }
    __syncthreads();
    // ---- Phase F1: P output (wave0), state writeback (waves1-2), next lpt/lst (wave3)
    if (wv == 0) {
      int row = lane >> 2, q = lane & 3;
      float s = 0.f;
      const float* hr = Hh[row];
      for (int c = q * 32; c < q * 32 + 32; ++c) s += hr[c] * w2[c];
      s += __shfl_xor(s, 1);
      s += __shfl_xor(s, 2);
      if (q == 0) P.out[(size_t)(b0 + row) * Ssz + t] = sigmoidf_(s + bo2);
    } else if (wv == 1 || wv == 2) {
      int which = wv - 1;
      bf16* dst = (which == 0) ? P.proSt : P.skSt;
      for (int it = 0; it < 4; ++it) {
        int row = it * 4 + (lane >> 4);
        int c0 = (lane & 15) * 8;
        *(bf16x8*)&dst[((size_t)(b0 + row) * Ssz + t) * Dsz + c0] =
            *(const bf16x8*)&STG[which][row][c0];
      }
    } else {
      if (t + 1 < Ssz) {
        if (lane < 16) lptS[lane] = P.lpt[(b0 + lane) * Ssz + t + 1];
        else if (lane < 32) lstS[lane - 16] = P.lst[(b0 + lane - 16) * Ssz + t + 1];
      }
    }
    __syncthreads();
    // ---- Phase F2: gathers for t+1
    if (t + 1 < Ssz) {
      gatherState(t + 1);
      gatherNX(t + 1);
    }
    __syncthreads();
  }
}

extern "C" void kernel_launch(void* const* d_in, const int* in_sizes, int n_in,
                              void* d_out, int out_size, void* d_ws, size_t ws_size,
                              hipStream_t stream) {
  const int*   next_problem   = (const int*)d_in[3];
  const int*   next_skill     = (const int*)d_in[4];
  const int*   next_ans       = (const int*)d_in[5];
  const float* pro_embed      = (const float*)d_in[6];
  const float* skill_embed    = (const float*)d_in[7];
  const float* ans_embed      = (const float*)d_in[8];
  const float* time_embed     = (const float*)d_in[9];
  const float* ls_state       = (const float*)d_in[10];
  const float* pro_state0     = (const float*)d_in[11];
  const float* skill_state0   = (const float*)d_in[12];
  const float* akt_pro_diff   = (const float*)d_in[13];
  const float* akt_pro_change = (const float*)d_in[14];
  const float* W_pf = (const float*)d_in[15];
  const float* b_pf = (const float*)d_in[16];
  const float* W_sf = (const float*)d_in[17];
  const float* b_sf = (const float*)d_in[18];
  const float* W_af = (const float*)d_in[19];
  const float* b_af = (const float*)d_in[20];
  const float* W_ps = (const float*)d_in[21];
  const float* b_ps = (const float*)d_in[22];
  const float* W_ss = (const float*)d_in[23];
  const float* b_ss = (const float*)d_in[24];
  const float* W_as = (const float*)d_in[25];
  const float* b_as = (const float*)d_in[26];
  const float* W_o1 = (const float*)d_in[27];
  const float* b_o1 = (const float*)d_in[28];
  const float* W_o2 = (const float*)d_in[29];
  const float* b_o2 = (const float*)d_in[30];

  char* ws = (char*)d_ws;
  size_t off = 0;
  auto alloc = [&](size_t bytes) -> void* {
    void* p = ws + off;
    off += bytes;
    off = (off + 255) & ~(size_t)255;
    return p;
  };
  bf16*  proSt = (bf16*)alloc((size_t)Bsz * Ssz * Dsz * 2);
  bf16*  skSt  = (bf16*)alloc((size_t)Bsz * Ssz * Dsz * 2);
  int*   lpt   = (int*)alloc((size_t)Bsz * Ssz * 4);
  int*   lst   = (int*)alloc((size_t)Bsz * Ssz * 4);
  float* TGEp  = (float*)alloc(200 * 128 * 4);
  float* TGEs  = (float*)alloc(200 * 128 * 4);
  float* cAF   = (float*)alloc(128 * 4);
  bf16*  PWpf  = (bf16*)alloc(128 * 128 * 2);
  bf16*  PWsf  = (bf16*)alloc(128 * 128 * 2);
  bf16*  PWaf  = (bf16*)alloc(128 * 128 * 2);
  bf16*  PWps  = (bf16*)alloc(256 * 128 * 2);
  bf16*  PWss  = (bf16*)alloc(256 * 128 * 2);
  bf16*  PWas  = (bf16*)alloc(256 * 128 * 2);
  bf16*  PWo1  = (bf16*)alloc(512 * 128 * 2);
  if (off > ws_size) {
    // workspace too small: emit NaN pattern so the failure mode is identifiable
    hipMemsetAsync(d_out, 0xFF, (size_t)out_size * 4, stream);
    return;
  }

  k_lastseen<<<Bsz, 256, 0, stream>>>(next_problem, next_skill, lpt, lst);
  k_pack<<<8,  256, 0, stream>>>(W_pf, PWpf, 128);
  k_pack<<<8,  256, 0, stream>>>(W_sf, PWsf, 128);
  k_pack<<<8,  256, 0, stream>>>(W_af, PWaf, 128);
  k_pack<<<16, 256, 0, stream>>>(W_ps, PWps, 256);
  k_pack<<<16, 256, 0, stream>>>(W_ss, PWss, 256);
  k_pack<<<16, 256, 0, stream>>>(W_as, PWas, 256);
  k_pack<<<32, 256, 0, stream>>>(W_o1, PWo1, 512);
  k_tge<<<200, 128, 0, stream>>>(time_embed, W_pf, b_pf, TGEp);
  k_tge<<<200, 128, 0, stream>>>(time_embed, W_sf, b_sf, TGEs);
  k_tge<<<1,   128, 0, stream>>>(time_embed + 128, W_af, b_af, cAF);

  MainParams mp;
  mp.next_problem = next_problem; mp.next_skill = next_skill; mp.next_ans = next_ans;
  mp.pro_embed = pro_embed; mp.skill_embed = skill_embed; mp.ans_embed = ans_embed;
  mp.akt_pro_diff = akt_pro_diff; mp.akt_pro_change = akt_pro_change;
  mp.ls_state = ls_state; mp.pro_state0 = pro_state0; mp.skill_state0 = skill_state0;
  mp.lpt = lpt; mp.lst = lst;
  mp.TGEp = TGEp; mp.TGEs = TGEs; mp.cAF = cAF;
  mp.PWpf = PWpf; mp.PWsf = PWsf; mp.PWaf = PWaf;
  mp.PWps = PWps; mp.PWss = PWss; mp.PWas = PWas; mp.PWo1 = PWo1;
  mp.b_ps = b_ps; mp.b_ss = b_ss; mp.b_as = b_as; mp.b_o1 = b_o1;
  mp.W_o2 = W_o2; mp.b_o2 = b_o2;
  mp.proSt = proSt; mp.skSt = skSt;
  mp.out = (float*)d_out;

  k_main<<<NBLK, 256, 0, stream>>>(mp);
}

// Round 2
// 820.643 us; speedup vs baseline: 1.9400x; 1.9400x over previous
//
#include <hip/hip_runtime.h>
#include <hip/hip_bf16.h>

typedef __bf16 bf16;
typedef bf16 bf16x8 __attribute__((ext_vector_type(8)));
typedef bf16 bf16x4 __attribute__((ext_vector_type(4)));
typedef float f32x4 __attribute__((ext_vector_type(4)));
typedef unsigned short u16;

#define Bsz 512
#define Ssz 199
#define Dsz 128
#define GR 16
#define NBLK (Bsz / GR)
#define BTot (Bsz * Ssz)

__device__ __forceinline__ float sigmoidf_(float x) { return 1.f / (1.f + __expf(-x)); }
__device__ __forceinline__ float tanhf_(float x) {
  float xc = fminf(fmaxf(x, -15.f), 15.f);
  float e = __expf(2.f * xc);
  return (e - 1.f) / (e + 1.f);
}
__device__ __forceinline__ f32x4 mfma16(bf16x8 a, bf16x8 b, f32x4 c) {
  return __builtin_amdgcn_mfma_f32_16x16x32_bf16(a, b, c, 0, 0, 0);
}
__device__ __forceinline__ bf16x8 ldfrag(const bf16* PW, int KS, int nt, int ks, int lane) {
  return *(const bf16x8*)&PW[(size_t)((nt * KS + ks) * 64 + lane) * 8];
}

// ---------------- K1: last-seen time tables ----------------
__global__ void k_lastseen(const int* __restrict__ np_, const int* __restrict__ ns_,
                           int* __restrict__ lpt, int* __restrict__ lst) {
  __shared__ unsigned short tabP[20000];
  __shared__ unsigned short tabS[500];
  __shared__ int pbuf[Ssz], sbuf[Ssz];
  int b = blockIdx.x;
  for (int i = threadIdx.x; i < 20000; i += blockDim.x) tabP[i] = 0;
  for (int i = threadIdx.x; i < 500; i += blockDim.x) tabS[i] = 0;
  for (int i = threadIdx.x; i < Ssz; i += blockDim.x) {
    pbuf[i] = np_[b * Ssz + i];
    sbuf[i] = ns_[b * Ssz + i];
  }
  __syncthreads();
  if (threadIdx.x == 0) {
    for (int t = 0; t < Ssz; ++t) {
      int p = pbuf[t], s = sbuf[t];
      lpt[b * Ssz + t] = tabP[p]; tabP[p] = (unsigned short)t;
      lst[b * Ssz + t] = tabS[s]; tabS[s] = (unsigned short)t;
    }
  }
}

// ---------------- K2: pack weights into MFMA B-fragment layout ----------------
__global__ void k_pack(const float* __restrict__ W, bf16* __restrict__ dst, int K) {
  int g = blockIdx.x * blockDim.x + threadIdx.x;
  int KS = K / 32;
  int total = 8 * KS * 64;
  if (g >= total) return;
  int l = g & 63;
  int ks = (g >> 6) % KS;
  int nt = (g >> 6) / KS;
  int col = nt * 16 + (l & 15);
  int k0 = ks * 32 + (l >> 4) * 8;
  bf16x8 v;
  for (int j = 0; j < 8; ++j) v[j] = (bf16)W[(size_t)(k0 + j) * 128 + col];
  *(bf16x8*)&dst[(size_t)g * 8] = v;
}

// ---------------- K3: time-embedding projections (bias folded) ----------------
__global__ void k_tge(const float* __restrict__ TE, const float* __restrict__ W,
                      const float* __restrict__ bias, float* __restrict__ dst) {
  __shared__ float te[128];
  int d = blockIdx.x, n = threadIdx.x;
  te[n] = TE[d * 128 + n];
  __syncthreads();
  float acc = bias[n];
  for (int k = 0; k < 128; ++k) acc += te[k] * W[(size_t)(128 + k) * 128 + n];
  dst[d * 128 + n] = acc;
}

// ---------------- main recurrent kernel ----------------
struct MainParams {
  const int *next_problem, *next_skill, *next_ans;
  const float *pro_embed, *skill_embed, *ans_embed;
  const float *akt_pro_diff, *akt_pro_change;
  const float *ls_state, *pro_state0, *skill_state0;
  const int *lpt, *lst;
  const float *TGEp, *TGEs, *cAF;
  const bf16 *PWpf, *PWsf, *PWaf, *PWps, *PWss, *PWas, *PWo1;
  const float *b_ps, *b_ss, *b_as, *b_o1, *W_o2, *b_o2;
  bf16 *proSt, *skSt;
  bf16 *Sla, *Slbp, *Slbs;  // gated-state dump for deferred head (IH==0)
  float *out;
};

// IH=1: inline head (fallback when ws too small). IH=0: defer head to k_head.
template <int IH>
__global__ void __launch_bounds__(512, 2) k_main(MainParams P) {
  const int b0 = blockIdx.x * GR;
  const int tid = threadIdx.x;
  const int lane = tid & 63;
  const int wv = tid >> 6;        // 0..7, wave owns cols [wv*16, wv*16+16)
  const int r32 = tid >> 5;       // 0..15 gather row
  const int c4 = (tid & 31) * 4;  // gather col group (4 elems)
  const int arow = lane & 15, apos = (lane >> 4) * 8;
  const int rb = (lane >> 4) * 4;
  const int cA = wv * 16 + (lane & 15);

  __shared__ __align__(16) bf16 Ala[16][136], Albp[16][136], Albs[16][136], AnX[16][136];
  __shared__ __align__(16) bf16 Anpe[IH ? 16 : 1][136];
  __shared__ __align__(16) float GPp[16][128], GPs[16][128];
  __shared__ __align__(16) bf16 STG[2][16][128];
  __shared__ float Hh[IH ? 16 : 1][132];
  __shared__ float Hpart[IH ? 16 : 1][16];
  __shared__ float w2s[IH ? 128 : 1];
  __shared__ u16 lptL[GR * Ssz], lstL[GR * Ssz], npL[GR * Ssz], nsnaL[GR * Ssz];

  // ---- register-resident weight slices for this wave ----
  bf16x8 Wpf[4], Wsf[4], Waf[4], Wps[8], Wss[8], Was[8];
#pragma unroll
  for (int ks = 0; ks < 4; ++ks) {
    Wpf[ks] = ldfrag(P.PWpf, 4, wv, ks, lane);
    Wsf[ks] = ldfrag(P.PWsf, 4, wv, ks, lane);
    Waf[ks] = ldfrag(P.PWaf, 4, wv, ks, lane);
  }
#pragma unroll
  for (int ks = 0; ks < 8; ++ks) {
    Wps[ks] = ldfrag(P.PWps, 8, wv, ks, lane);
    Wss[ks] = ldfrag(P.PWss, 8, wv, ks, lane);
    Was[ks] = ldfrag(P.PWas, 8, wv, ks, lane);
  }
  const float bpsv = P.b_ps[cA], bssv = P.b_ss[cA], basv = P.b_as[cA], cafv = P.cAF[cA];
  float bo1v = 0.f, bo2 = 0.f;
  if (IH) {
    bo1v = P.b_o1[cA];
    bo2 = P.b_o2[0];
    if (tid < 128) w2s[tid] = P.W_o2[tid];
  }

  // ---- preload per-row index streams into LDS (u16) ----
  for (int i = tid; i < GR * Ssz; i += 512) {
    int r = i / Ssz, tt = i - r * Ssz;
    int bt = (b0 + r) * Ssz + tt;
    lptL[i] = (u16)P.lpt[bt];
    lstL[i] = (u16)P.lst[bt];
    npL[i] = (u16)P.next_problem[bt];
    nsnaL[i] = (u16)((P.next_skill[bt] << 1) | P.next_ans[bt]);
  }
  __syncthreads();

  // ---- t = 0 gather ----
  {
    bf16x4 va, vp, vs;
    for (int j = 0; j < 4; ++j) {
      va[j] = (bf16)P.ls_state[c4 + j];
      vp[j] = (bf16)P.pro_state0[c4 + j];
      vs[j] = (bf16)P.skill_state0[c4 + j];
    }
    *(bf16x4*)&Ala[r32][c4] = va;
    *(bf16x4*)&Albp[r32][c4] = vp;
    *(bf16x4*)&Albs[r32][c4] = vs;
    *(f32x4*)&GPp[r32][c4] = *(const f32x4*)&P.TGEp[c4];
    *(f32x4*)&GPs[r32][c4] = *(const f32x4*)&P.TGEs[c4];
    int ii = r32 * Ssz;
    int np = npL[ii];
    int sa = nsnaL[ii];
    int ns = sa >> 1, na = sa & 1;
    float diff = P.akt_pro_diff[np];
    f32x4 pe = *(const f32x4*)&P.pro_embed[(size_t)np * Dsz + c4];
    f32x4 se = *(const f32x4*)&P.skill_embed[(size_t)ns * Dsz + c4];
    f32x4 ch = *(const f32x4*)&P.akt_pro_change[(size_t)ns * Dsz + c4];
    f32x4 ae = *(const f32x4*)&P.ans_embed[(size_t)na * Dsz + c4];
    bf16x4 vx, vn;
    for (int j = 0; j < 4; ++j) {
      float f = pe[j] + se[j] + diff * ch[j];
      vn[j] = (bf16)f;
      vx[j] = (bf16)(f + ae[j]);
    }
    *(bf16x4*)&AnX[r32][c4] = vx;
    if (IH) *(bf16x4*)&Anpe[r32][c4] = vn;
  }
  __syncthreads();

  for (int t = 0; t < Ssz; ++t) {
    // ---- prefetch for t+1 (issued before MFMAs; consumed in F) ----
    int lpN = 0, lsN = 0;
    bf16x4 pPro{}, pSk{};
    f32x4 pGp{}, pGs{}, pe{}, se{}, ch{}, ae{};
    float diff = 0.f;
    if (t + 1 < Ssz) {
      int ii = r32 * Ssz + t + 1;
      lpN = lptL[ii];
      lsN = lstL[ii];
      int np = npL[ii];
      int sa = nsnaL[ii];
      int ns = sa >> 1, na = sa & 1;
      if (lpN != t)
        pPro = *(const bf16x4*)&P.proSt[((size_t)(b0 + r32) * Ssz + lpN) * Dsz + c4];
      if (lsN != t)
        pSk = *(const bf16x4*)&P.skSt[((size_t)(b0 + r32) * Ssz + lsN) * Dsz + c4];
      pGp = *(const f32x4*)&P.TGEp[(size_t)(t + 1 - lpN) * Dsz + c4];
      pGs = *(const f32x4*)&P.TGEs[(size_t)(t + 1 - lsN) * Dsz + c4];
      diff = P.akt_pro_diff[np];
      pe = *(const f32x4*)&P.pro_embed[(size_t)np * Dsz + c4];
      se = *(const f32x4*)&P.skill_embed[(size_t)ns * Dsz + c4];
      ch = *(const f32x4*)&P.akt_pro_change[(size_t)ns * Dsz + c4];
      ae = *(const f32x4*)&P.ans_embed[(size_t)na * Dsz + c4];
    }
    // inline head: finalize previous step's P (reads Hpart from F(t-1))
    if (IH && t > 0 && tid < 16) {
      float s = 0.f;
      for (int k = 0; k < 16; ++k) s += Hpart[tid][k];
      P.out[(size_t)(b0 + tid) * Ssz + (t - 1)] = sigmoidf_(s + bo2);
    }
    // ---- B: gate matmuls (K=128), weights in registers ----
    f32x4 dpf{}, dsf{}, daf{};
#pragma unroll
    for (int ks = 0; ks < 4; ++ks) {
      bf16x8 ap = *(const bf16x8*)&Albp[arow][ks * 32 + apos];
      bf16x8 av = *(const bf16x8*)&Albs[arow][ks * 32 + apos];
      bf16x8 aa = *(const bf16x8*)&Ala[arow][ks * 32 + apos];
      dpf = mfma16(ap, Wpf[ks], dpf);
      dsf = mfma16(av, Wsf[ks], dsf);
      daf = mfma16(aa, Waf[ks], daf);
    }
    __syncthreads();
    // ---- C: gate epilogue ----
#pragma unroll
    for (int r = 0; r < 4; ++r) {
      int row = rb + r;
      float gp = sigmoidf_(dpf[r] + GPp[row][cA]);
      Albp[row][cA] = (bf16)((float)Albp[row][cA] * gp);
      float gs = sigmoidf_(dsf[r] + GPs[row][cA]);
      Albs[row][cA] = (bf16)((float)Albs[row][cA] * gs);
      float ga = sigmoidf_(daf[r] + cafv);
      Ala[row][cA] = (bf16)((float)Ala[row][cA] * ga);
    }
    __syncthreads();
    // ---- D: update matmuls (K=256) [+ inline head K=512] ----
    f32x4 uas{}, ups{}, uss{}, hh{};
#pragma unroll
    for (int ks = 0; ks < 4; ++ks) {
      bf16x8 aa = *(const bf16x8*)&Ala[arow][ks * 32 + apos];
      bf16x8 ap = *(const bf16x8*)&Albp[arow][ks * 32 + apos];
      bf16x8 av = *(const bf16x8*)&Albs[arow][ks * 32 + apos];
      bf16x8 ax = *(const bf16x8*)&AnX[arow][ks * 32 + apos];
      uas = mfma16(aa, Was[ks], uas);
      uas = mfma16(ax, Was[ks + 4], uas);
      ups = mfma16(ap, Wps[ks], ups);
      ups = mfma16(ax, Wps[ks + 4], ups);
      uss = mfma16(av, Wss[ks], uss);
      uss = mfma16(ax, Wss[ks + 4], uss);
      if (IH) {
        bf16x8 an = *(const bf16x8*)&Anpe[arow][ks * 32 + apos];
        hh = mfma16(aa, ldfrag(P.PWo1, 16, wv, ks, lane), hh);
        hh = mfma16(ap, ldfrag(P.PWo1, 16, wv, ks + 4, lane), hh);
        hh = mfma16(av, ldfrag(P.PWo1, 16, wv, ks + 8, lane), hh);
        hh = mfma16(an, ldfrag(P.PWo1, 16, wv, ks + 12, lane), hh);
      }
    }
    __syncthreads();
    // ---- E: update epilogue ----
#pragma unroll
    for (int r = 0; r < 4; ++r) {
      int row = rb + r;
      float lav = (float)Ala[row][cA];
      float lbpv = (float)Albp[row][cA];
      float lbsv = (float)Albs[row][cA];
      Ala[row][cA] = (bf16)(lav + tanhf_(uas[r] + basv));
      STG[0][row][cA] = (bf16)(lbpv + tanhf_(ups[r] + bpsv));
      STG[1][row][cA] = (bf16)(lbsv + tanhf_(uss[r] + bssv));
      if (!IH) P.Sla[((size_t)(b0 + row) * Ssz + t) * Dsz + cA] = (bf16)lav;
      if (IH) Hh[row][cA] = fmaxf(hh[r] + bo1v, 0.f);
    }
    __syncthreads();
    // ---- F: writebacks, gated-state dump, install t+1 gathers ----
    if (!IH) {
      *(bf16x4*)&P.Slbp[((size_t)(b0 + r32) * Ssz + t) * Dsz + c4] =
          *(const bf16x4*)&Albp[r32][c4];
      *(bf16x4*)&P.Slbs[((size_t)(b0 + r32) * Ssz + t) * Dsz + c4] =
          *(const bf16x4*)&Albs[r32][c4];
    }
    bf16x4 npv = *(const bf16x4*)&STG[0][r32][c4];
    bf16x4 nsv = *(const bf16x4*)&STG[1][r32][c4];
    *(bf16x4*)&P.proSt[((size_t)(b0 + r32) * Ssz + t) * Dsz + c4] = npv;
    *(bf16x4*)&P.skSt[((size_t)(b0 + r32) * Ssz + t) * Dsz + c4] = nsv;
    if (t + 1 < Ssz) {
      *(bf16x4*)&Albp[r32][c4] = (lpN == t) ? npv : pPro;
      *(bf16x4*)&Albs[r32][c4] = (lsN == t) ? nsv : pSk;
      *(f32x4*)&GPp[r32][c4] = pGp;
      *(f32x4*)&GPs[r32][c4] = pGs;
      bf16x4 vx, vn;
      for (int j = 0; j < 4; ++j) {
        float f = pe[j] + se[j] + diff * ch[j];
        vn[j] = (bf16)f;
        vx[j] = (bf16)(f + ae[j]);
      }
      *(bf16x4*)&AnX[r32][c4] = vx;
      if (IH) *(bf16x4*)&Anpe[r32][c4] = vn;
    }
    if (IH && tid < 256) {
      int row = tid >> 4, cg = tid & 15;
      float s = 0.f;
      for (int j = 0; j < 8; ++j) s += Hh[row][cg * 8 + j] * w2s[cg * 8 + j];
      Hpart[row][cg] = s;
    }
    __syncthreads();
  }
  if (IH && tid < 16) {
    float s = 0.f;
    for (int k = 0; k < 16; ++k) s += Hpart[tid][k];
    P.out[(size_t)(b0 + tid) * Ssz + (Ssz - 1)] = sigmoidf_(s + bo2);
  }
}

// ---------------- deferred head: P = sigmoid(relu(final@W1+b1)@W2+b2) ----------------
struct HeadParams {
  const bf16 *Sla, *Slbp, *Slbs, *PWo1;
  const int *next_problem, *next_skill;
  const float *pro_embed, *skill_embed, *akt_pro_diff, *akt_pro_change;
  const float *b_o1, *W_o2, *b_o2;
  float *out;
};

__global__ void k_head(HeadParams P) {
  const int bt0 = blockIdx.x * 16;
  const int tid = threadIdx.x, lane = tid & 63, wv = tid >> 6;
  const int r16 = tid >> 4, c8 = (tid & 15) * 8;
  const int arow = lane & 15, apos = (lane >> 4) * 8;
  const int rb = (lane >> 4) * 4;
  const int nt0 = wv, nt1 = wv + 4;
  const int cAh = nt0 * 16 + (lane & 15), cBh = nt1 * 16 + (lane & 15);
  __shared__ __align__(16) bf16 Af[16][520];
  __shared__ float Hh[16][132];
  __shared__ float Hpart[16][16];
  __shared__ float w2s[128];
  if (tid < 128) w2s[tid] = P.W_o2[tid];
  {
    int bt = bt0 + r16;
    *(bf16x8*)&Af[r16][c8] = *(const bf16x8*)&P.Sla[(size_t)bt * 128 + c8];
    *(bf16x8*)&Af[r16][128 + c8] = *(const bf16x8*)&P.Slbp[(size_t)bt * 128 + c8];
    *(bf16x8*)&Af[r16][256 + c8] = *(const bf16x8*)&P.Slbs[(size_t)bt * 128 + c8];
    int np = P.next_problem[bt], ns = P.next_skill[bt];
    float diff = P.akt_pro_diff[np];
    f32x4 p0 = *(const f32x4*)&P.pro_embed[(size_t)np * 128 + c8];
    f32x4 p1 = *(const f32x4*)&P.pro_embed[(size_t)np * 128 + c8 + 4];
    f32x4 s0 = *(const f32x4*)&P.skill_embed[(size_t)ns * 128 + c8];
    f32x4 s1 = *(const f32x4*)&P.skill_embed[(size_t)ns * 128 + c8 + 4];
    f32x4 c0 = *(const f32x4*)&P.akt_pro_change[(size_t)ns * 128 + c8];
    f32x4 c1 = *(const f32x4*)&P.akt_pro_change[(size_t)ns * 128 + c8 + 4];
    bf16x8 vn;
    for (int j = 0; j < 4; ++j) {
      vn[j] = (bf16)(p0[j] + s0[j] + diff * c0[j]);
      vn[j + 4] = (bf16)(p1[j] + s1[j] + diff * c1[j]);
    }
    *(bf16x8*)&Af[r16][384 + c8] = vn;
  }
  __syncthreads();
  f32x4 h0{}, h1{};
#pragma unroll
  for (int ks = 0; ks < 16; ++ks) {
    bf16x8 a = *(const bf16x8*)&Af[arow][ks * 32 + apos];
    h0 = mfma16(a, ldfrag(P.PWo1, 16, nt0, ks, lane), h0);
    h1 = mfma16(a, ldfrag(P.PWo1, 16, nt1, ks, lane), h1);
  }
  const float bo1A = P.b_o1[cAh], bo1B = P.b_o1[cBh];
  for (int r = 0; r < 4; ++r) {
    Hh[rb + r][cAh] = fmaxf(h0[r] + bo1A, 0.f);
    Hh[rb + r][cBh] = fmaxf(h1[r] + bo1B, 0.f);
  }
  __syncthreads();
  {
    int row = tid >> 4, cg = tid & 15;
    float s = 0.f;
    for (int j = 0; j < 8; ++j) s += Hh[row][cg * 8 + j] * w2s[cg * 8 + j];
    Hpart[row][cg] = s;
  }
  __syncthreads();
  if (tid < 16) {
    float s = 0.f;
    for (int k = 0; k < 16; ++k) s += Hpart[tid][k];
    P.out[bt0 + tid] = sigmoidf_(s + P.b_o2[0]);
  }
}

extern "C" void kernel_launch(void* const* d_in, const int* in_sizes, int n_in,
                              void* d_out, int out_size, void* d_ws, size_t ws_size,
                              hipStream_t stream) {
  const int* next_problem = (const int*)d_in[3];
  const int* next_skill = (const int*)d_in[4];
  const int* next_ans = (const int*)d_in[5];
  const float* pro_embed = (const float*)d_in[6];
  const float* skill_embed = (const float*)d_in[7];
  const float* ans_embed = (const float*)d_in[8];
  const float* time_embed = (const float*)d_in[9];
  const float* ls_state = (const float*)d_in[10];
  const float* pro_state0 = (const float*)d_in[11];
  const float* skill_state0 = (const float*)d_in[12];
  const float* akt_pro_diff = (const float*)d_in[13];
  const float* akt_pro_change = (const float*)d_in[14];
  const float* W_pf = (const float*)d_in[15];
  const float* b_pf = (const float*)d_in[16];
  const float* W_sf = (const float*)d_in[17];
  const float* b_sf = (const float*)d_in[18];
  const float* W_af = (const float*)d_in[19];
  const float* b_af = (const float*)d_in[20];
  const float* W_ps = (const float*)d_in[21];
  const float* b_ps = (const float*)d_in[22];
  const float* W_ss = (const float*)d_in[23];
  const float* b_ss = (const float*)d_in[24];
  const float* W_as = (const float*)d_in[25];
  const float* b_as = (const float*)d_in[26];
  const float* W_o1 = (const float*)d_in[27];
  const float* b_o1 = (const float*)d_in[28];
  const float* W_o2 = (const float*)d_in[29];
  const float* b_o2 = (const float*)d_in[30];

  char* ws = (char*)d_ws;
  size_t off = 0;
  auto alloc = [&](size_t bytes) -> void* {
    void* p = ws + off;
    off += bytes;
    off = (off + 255) & ~(size_t)255;
    return p;
  };
  bf16* proSt = (bf16*)alloc((size_t)Bsz * Ssz * Dsz * 2);
  bf16* skSt = (bf16*)alloc((size_t)Bsz * Ssz * Dsz * 2);
  int* lpt = (int*)alloc((size_t)Bsz * Ssz * 4);
  int* lst = (int*)alloc((size_t)Bsz * Ssz * 4);
  float* TGEp = (float*)alloc(200 * 128 * 4);
  float* TGEs = (float*)alloc(200 * 128 * 4);
  float* cAF = (float*)alloc(128 * 4);
  bf16* PWpf = (bf16*)alloc(128 * 128 * 2);
  bf16* PWsf = (bf16*)alloc(128 * 128 * 2);
  bf16* PWaf = (bf16*)alloc(128 * 128 * 2);
  bf16* PWps = (bf16*)alloc(256 * 128 * 2);
  bf16* PWss = (bf16*)alloc(256 * 128 * 2);
  bf16* PWas = (bf16*)alloc(256 * 128 * 2);
  bf16* PWo1 = (bf16*)alloc(512 * 128 * 2);
  size_t off_common = off;
  bf16* Sla = (bf16*)alloc((size_t)BTot * Dsz * 2);
  bf16* Slbp = (bf16*)alloc((size_t)BTot * Dsz * 2);
  bf16* Slbs = (bf16*)alloc((size_t)BTot * Dsz * 2);
  size_t off_defer = off;

  bool defer = (off_defer <= ws_size);
  if (!defer && off_common > ws_size) {
    hipMemsetAsync(d_out, 0xFF, (size_t)out_size * 4, stream);
    return;
  }

  k_lastseen<<<Bsz, 256, 0, stream>>>(next_problem, next_skill, lpt, lst);
  k_pack<<<8, 256, 0, stream>>>(W_pf, PWpf, 128);
  k_pack<<<8, 256, 0, stream>>>(W_sf, PWsf, 128);
  k_pack<<<8, 256, 0, stream>>>(W_af, PWaf, 128);
  k_pack<<<16, 256, 0, stream>>>(W_ps, PWps, 256);
  k_pack<<<16, 256, 0, stream>>>(W_ss, PWss, 256);
  k_pack<<<16, 256, 0, stream>>>(W_as, PWas, 256);
  k_pack<<<32, 256, 0, stream>>>(W_o1, PWo1, 512);
  k_tge<<<200, 128, 0, stream>>>(time_embed, W_pf, b_pf, TGEp);
  k_tge<<<200, 128, 0, stream>>>(time_embed, W_sf, b_sf, TGEs);
  k_tge<<<1, 128, 0, stream>>>(time_embed + 128, W_af, b_af, cAF);

  MainParams mp;
  mp.next_problem = next_problem; mp.next_skill = next_skill; mp.next_ans = next_ans;
  mp.pro_embed = pro_embed; mp.skill_embed = skill_embed; mp.ans_embed = ans_embed;
  mp.akt_pro_diff = akt_pro_diff; mp.akt_pro_change = akt_pro_change;
  mp.ls_state = ls_state; mp.pro_state0 = pro_state0; mp.skill_state0 = skill_state0;
  mp.lpt = lpt; mp.lst = lst;
  mp.TGEp = TGEp; mp.TGEs = TGEs; mp.cAF = cAF;
  mp.PWpf = PWpf; mp.PWsf = PWsf; mp.PWaf = PWaf;
  mp.PWps = PWps; mp.PWss = PWss; mp.PWas = PWas; mp.PWo1 = PWo1;
  mp.b_ps = b_ps; mp.b_ss = b_ss; mp.b_as = b_as; mp.b_o1 = b_o1;
  mp.W_o2 = W_o2; mp.b_o2 = b_o2;
  mp.proSt = proSt; mp.skSt = skSt;
  mp.Sla = Sla; mp.Slbp = Slbp; mp.Slbs = Slbs;
  mp.out = (float*)d_out;

  if (defer) {
    k_main<0><<<NBLK, 512, 0, stream>>>(mp);
    HeadParams hp;
    hp.Sla = Sla; hp.Slbp = Slbp; hp.Slbs = Slbs; hp.PWo1 = PWo1;
    hp.next_problem = next_problem; hp.next_skill = next_skill;
    hp.pro_embed = pro_embed; hp.skill_embed = skill_embed;
    hp.akt_pro_diff = akt_pro_diff; hp.akt_pro_change = akt_pro_change;
    hp.b_o1 = b_o1; hp.W_o2 = W_o2; hp.b_o2 = b_o2;
    hp.out = (float*)d_out;
    k_head<<<BTot / 16, 256, 0, stream>>>(hp);
  } else {
    k_main<1><<<NBLK, 512, 0, stream>>>(mp);
  }
}

// Round 3
// 686.713 us; speedup vs baseline: 2.3184x; 1.1950x over previous
//
#include <hip/hip_runtime.h>
#include <hip/hip_bf16.h>

typedef __bf16 bf16;
typedef bf16 bf16x8 __attribute__((ext_vector_type(8)));
typedef bf16 bf16x4 __attribute__((ext_vector_type(4)));
typedef float f32x4 __attribute__((ext_vector_type(4)));
typedef unsigned int u32;
typedef unsigned short u16;

#define Bsz 512
#define Ssz 199
#define Dsz 128
#define GR 16
#define NBLK (Bsz / GR)
#define BTot (Bsz * Ssz)

__device__ __forceinline__ float fsig(float x) {
  return __builtin_amdgcn_rcpf(1.f + __builtin_amdgcn_exp2f(x * -1.44269504f));
}
__device__ __forceinline__ float ftanh(float x) {
  return 1.f - 2.f * __builtin_amdgcn_rcpf(1.f + __builtin_amdgcn_exp2f(x * 2.88539008f));
}
__device__ __forceinline__ f32x4 mfma16(bf16x8 a, bf16x8 b, f32x4 c) {
  return __builtin_amdgcn_mfma_f32_16x16x32_bf16(a, b, c, 0, 0, 0);
}
__device__ __forceinline__ bf16x8 ldfrag(const bf16* PW, int KS, int nt, int ks, int lane) {
  return *(const bf16x8*)&PW[(size_t)((nt * KS + ks) * 64 + lane) * 8];
}
// raw workgroup barrier: orders LDS only; global loads stay in flight across it
__device__ __forceinline__ void barL() {
  __builtin_amdgcn_sched_barrier(0);
  asm volatile("s_waitcnt lgkmcnt(0)" ::: "memory");
  __builtin_amdgcn_s_barrier();
  __builtin_amdgcn_sched_barrier(0);
}

// ---------------- K1: packed per-(b,t) index stream: lpt | lst<<8 | na<<16 ----------------
__global__ void k_idx(const int* __restrict__ np_, const int* __restrict__ ns_,
                      const int* __restrict__ na_, u32* __restrict__ idx) {
  __shared__ u16 tabP[20000];
  __shared__ u16 tabS[500];
  __shared__ u16 pb[Ssz], sb[Ssz];
  __shared__ unsigned char ab[Ssz];
  int b = blockIdx.x;
  for (int i = threadIdx.x; i < 20000; i += blockDim.x) tabP[i] = 0;
  for (int i = threadIdx.x; i < 500; i += blockDim.x) tabS[i] = 0;
  for (int i = threadIdx.x; i < Ssz; i += blockDim.x) {
    pb[i] = (u16)np_[b * Ssz + i];
    sb[i] = (u16)ns_[b * Ssz + i];
    ab[i] = (unsigned char)na_[b * Ssz + i];
  }
  __syncthreads();
  if (threadIdx.x == 0) {
    for (int t = 0; t < Ssz; ++t) {
      int p = pb[t], s = sb[t];
      idx[b * Ssz + t] = (u32)tabP[p] | ((u32)tabS[s] << 8) | ((u32)ab[t] << 16);
      tabP[p] = (u16)t;
      tabS[s] = (u16)t;
    }
  }
}

// ---------------- K2: pack weights into MFMA B-fragment layout ----------------
__global__ void k_pack(const float* __restrict__ W, bf16* __restrict__ dst, int K) {
  int g = blockIdx.x * blockDim.x + threadIdx.x;
  int KS = K / 32;
  int total = 8 * KS * 64;
  if (g >= total) return;
  int l = g & 63;
  int ks = (g >> 6) % KS;
  int nt = (g >> 6) / KS;
  int col = nt * 16 + (l & 15);
  int k0 = ks * 32 + (l >> 4) * 8;
  bf16x8 v;
  for (int j = 0; j < 8; ++j) v[j] = (bf16)W[(size_t)(k0 + j) * 128 + col];
  *(bf16x8*)&dst[(size_t)g * 8] = v;
}

// ---------------- K3: time-embedding projections (bias folded) ----------------
__global__ void k_tge(const float* __restrict__ TE, const float* __restrict__ W,
                      const float* __restrict__ bias, float* __restrict__ dst) {
  __shared__ float te[128];
  int d = blockIdx.x, n = threadIdx.x;
  te[n] = TE[d * 128 + n];
  __syncthreads();
  float acc = bias[n];
  for (int k = 0; k < 128; ++k) acc += te[k] * W[(size_t)(128 + k) * 128 + n];
  dst[d * 128 + n] = acc;
}

// ---------------- K4: npe embedding stream (bf16) ----------------
__global__ void k_embed(const int* __restrict__ np_, const int* __restrict__ ns_,
                        const float* __restrict__ pe, const float* __restrict__ se,
                        const float* __restrict__ diff, const float* __restrict__ chg,
                        bf16* __restrict__ npe) {
  int g = blockIdx.x * 256 + threadIdx.x;
  int bt = g >> 5, cg = (g & 31) * 4;
  if (bt >= BTot) return;
  int p = np_[bt], s = ns_[bt];
  float d = diff[p];
  f32x4 a = *(const f32x4*)&pe[(size_t)p * 128 + cg];
  f32x4 b = *(const f32x4*)&se[(size_t)s * 128 + cg];
  f32x4 c = *(const f32x4*)&chg[(size_t)s * 128 + cg];
  bf16x4 v;
  for (int j = 0; j < 4; ++j) v[j] = (bf16)(a[j] + b[j] + d * c[j]);
  *(bf16x4*)&npe[(size_t)bt * 128 + cg] = v;
}

// ---------------- main recurrent kernel ----------------
struct MainParams {
  const int *next_problem, *next_skill;  // EMB==0 fallback
  const float *pro_embed, *skill_embed, *akt_pro_diff, *akt_pro_change;
  const float *ans_embed;
  const float *ls_state, *pro_state0, *skill_state0;
  const u32 *idx;
  const bf16 *npe;
  const float *TGEp, *TGEs, *cAF;
  const bf16 *PWpf, *PWsf, *PWaf, *PWps, *PWss, *PWas;
  const float *b_ps, *b_ss, *b_as;
  bf16 *proSt, *skSt, *Sla, *Slbp, *Slbs;
};

template <int EMB>
__global__ void __launch_bounds__(512) __attribute__((amdgpu_waves_per_eu(2, 2)))
k_main(MainParams P) {
  const int b0 = blockIdx.x * GR;
  const int tid = threadIdx.x;
  const int lane = tid & 63;
  const int wv = tid >> 6;        // 0..7: wave owns output cols [wv*16, wv*16+16)
  const int r32 = tid >> 5;       // 0..15: gather row
  const int c4 = (tid & 31) * 4;  // gather col group
  const int arow = lane & 15, apos = (lane >> 4) * 8;
  const int rb = (lane >> 4) * 4;
  const int cA = wv * 16 + (lane & 15);

  __shared__ __align__(16) bf16 Ala[16][136], Albp[16][136], Albs[16][136], AnX[16][136];
  __shared__ __align__(16) bf16 STG0[16][132], STG1[16][132], STGa[16][132];
  __shared__ u32 idxL[GR * Ssz];

  // ---- register-resident weight slices for this wave ----
  bf16x8 Wpf[4], Wsf[4], Waf[4], Wps[8], Wss[8], Was[8];
#pragma unroll
  for (int ks = 0; ks < 4; ++ks) {
    Wpf[ks] = ldfrag(P.PWpf, 4, wv, ks, lane);
    Wsf[ks] = ldfrag(P.PWsf, 4, wv, ks, lane);
    Waf[ks] = ldfrag(P.PWaf, 4, wv, ks, lane);
  }
#pragma unroll
  for (int ks = 0; ks < 8; ++ks) {
    Wps[ks] = ldfrag(P.PWps, 8, wv, ks, lane);
    Wss[ks] = ldfrag(P.PWss, 8, wv, ks, lane);
    Was[ks] = ldfrag(P.PWas, 8, wv, ks, lane);
  }
  const float bpsv = P.b_ps[cA], bssv = P.b_ss[cA], basv = P.b_as[cA], cafv = P.cAF[cA];
  float aeL[4], aeH[4];
#pragma unroll
  for (int j = 0; j < 4; ++j) {
    aeL[j] = P.ans_embed[c4 + j];
    aeH[j] = P.ans_embed[128 + c4 + j];
  }

  // ---- preload packed index stream (contiguous) ----
  for (int i = tid; i < GR * Ssz; i += 512) idxL[i] = P.idx[b0 * Ssz + i];
  __syncthreads();

  // ---- t = 0 state/gather init ----
  float gpc[4], gsc[4];
  {
    bf16x4 va, vp, vs;
    for (int j = 0; j < 4; ++j) {
      va[j] = (bf16)P.ls_state[c4 + j];
      vp[j] = (bf16)P.pro_state0[c4 + j];
      vs[j] = (bf16)P.skill_state0[c4 + j];
    }
    *(bf16x4*)&Ala[r32][c4] = va;
    *(bf16x4*)&Albp[r32][c4] = vp;
    *(bf16x4*)&Albs[r32][c4] = vs;
    u32 iw0 = idxL[r32 * Ssz];
    int na0 = (iw0 >> 16) & 1;
    f32x4 np0;
    if (EMB) {
      bf16x4 nb = *(const bf16x4*)&P.npe[((size_t)(b0 + r32) * Ssz) * Dsz + c4];
      for (int j = 0; j < 4; ++j) np0[j] = (float)nb[j];
    } else {
      int bt = (b0 + r32) * Ssz;
      int np = P.next_problem[bt], ns = P.next_skill[bt];
      float d = P.akt_pro_diff[np];
      f32x4 a = *(const f32x4*)&P.pro_embed[(size_t)np * 128 + c4];
      f32x4 b = *(const f32x4*)&P.skill_embed[(size_t)ns * 128 + c4];
      f32x4 c = *(const f32x4*)&P.akt_pro_change[(size_t)ns * 128 + c4];
      for (int j = 0; j < 4; ++j) np0[j] = a[j] + b[j] + d * c[j];
    }
    bf16x4 vx;
    for (int j = 0; j < 4; ++j) vx[j] = (bf16)(np0[j] + (na0 ? aeH[j] : aeL[j]));
    *(bf16x4*)&AnX[r32][c4] = vx;
#pragma unroll
    for (int r = 0; r < 4; ++r) {
      gpc[r] = P.TGEp[cA];  // t=0: lpt=lst=0 -> TGE row 0
      gsc[r] = P.TGEs[cA];
    }
  }
  __syncthreads();

  for (int t = 0; t < Ssz; ++t) {
    const bool pf = (t + 1 < Ssz);
    // ---- prefetch for t+1 (global loads; in flight across raw barriers) ----
    float gpn[4], gsn[4];
    bf16x4 pPro{}, pSk{}, pNp{};
    f32x4 pNpF{};
    u32 iwN = 0;
    if (pf) {
#pragma unroll
      for (int r = 0; r < 4; ++r) {
        u32 iw = idxL[(rb + r) * Ssz + t + 1];
        int lp = iw & 255, ls = (iw >> 8) & 255;
        gpn[r] = P.TGEp[(size_t)(t + 1 - lp) * Dsz + cA];
        gsn[r] = P.TGEs[(size_t)(t + 1 - ls) * Dsz + cA];
      }
      iwN = idxL[r32 * Ssz + t + 1];
      int lpN = iwN & 255, lsN = (iwN >> 8) & 255;
      if (lpN != t)
        pPro = *(const bf16x4*)&P.proSt[((size_t)(b0 + r32) * Ssz + lpN) * Dsz + c4];
      if (lsN != t)
        pSk = *(const bf16x4*)&P.skSt[((size_t)(b0 + r32) * Ssz + lsN) * Dsz + c4];
      if (EMB) {
        pNp = *(const bf16x4*)&P.npe[((size_t)(b0 + r32) * Ssz + t + 1) * Dsz + c4];
      } else {
        int bt = (b0 + r32) * Ssz + t + 1;
        int np = P.next_problem[bt], ns = P.next_skill[bt];
        float d = P.akt_pro_diff[np];
        f32x4 a = *(const f32x4*)&P.pro_embed[(size_t)np * 128 + c4];
        f32x4 b = *(const f32x4*)&P.skill_embed[(size_t)ns * 128 + c4];
        f32x4 c = *(const f32x4*)&P.akt_pro_change[(size_t)ns * 128 + c4];
        for (int j = 0; j < 4; ++j) pNpF[j] = a[j] + b[j] + d * c[j];
      }
    }
    // ---- B: gate matmuls (K=128), weights in registers ----
    f32x4 dpf{}, dsf{}, daf{};
#pragma unroll
    for (int ks = 0; ks < 4; ++ks) {
      bf16x8 ap = *(const bf16x8*)&Albp[arow][ks * 32 + apos];
      bf16x8 av = *(const bf16x8*)&Albs[arow][ks * 32 + apos];
      bf16x8 aa = *(const bf16x8*)&Ala[arow][ks * 32 + apos];
      dpf = mfma16(ap, Wpf[ks], dpf);
      dsf = mfma16(av, Wsf[ks], dsf);
      daf = mfma16(aa, Waf[ks], daf);
    }
    barL();
    // ---- C: gate epilogue (gated values kept in f32 regs for E) ----
    float gP[4], gS[4], gA[4];
#pragma unroll
    for (int r = 0; r < 4; ++r) {
      int row = rb + r;
      float sp = (float)Albp[row][cA];
      float gv = sp * fsig(dpf[r] + gpc[r]);
      gP[r] = gv;
      Albp[row][cA] = (bf16)gv;
      float ss = (float)Albs[row][cA];
      float gw = ss * fsig(dsf[r] + gsc[r]);
      gS[r] = gw;
      Albs[row][cA] = (bf16)gw;
      float sa = (float)Ala[row][cA];
      float gx = sa * fsig(daf[r] + cafv);
      gA[r] = gx;
      Ala[row][cA] = (bf16)gx;
    }
    barL();
    // ---- D: update matmuls (K=256), weights in registers ----
    f32x4 uas{}, ups{}, uss{};
#pragma unroll
    for (int ks = 0; ks < 4; ++ks) {
      bf16x8 aa = *(const bf16x8*)&Ala[arow][ks * 32 + apos];
      bf16x8 ap = *(const bf16x8*)&Albp[arow][ks * 32 + apos];
      bf16x8 av = *(const bf16x8*)&Albs[arow][ks * 32 + apos];
      bf16x8 ax = *(const bf16x8*)&AnX[arow][ks * 32 + apos];
      uas = mfma16(aa, Was[ks], uas);
      uas = mfma16(ax, Was[ks + 4], uas);
      ups = mfma16(ap, Wps[ks], ups);
      ups = mfma16(ax, Wps[ks + 4], ups);
      uss = mfma16(av, Wss[ks], uss);
      uss = mfma16(ax, Wss[ks + 4], uss);
    }
    // ---- E: update epilogue (no barrier needed after D: acc deps are in-wave) ----
#pragma unroll
    for (int r = 0; r < 4; ++r) {
      int row = rb + r;
      STG0[row][cA] = (bf16)(gP[r] + ftanh(ups[r] + bpsv));
      STG1[row][cA] = (bf16)(gS[r] + ftanh(uss[r] + bssv));
      STGa[row][cA] = (bf16)(gA[r] + ftanh(uas[r] + basv));
    }
    barL();
    // ---- F: dumps, state writeback, install t+1 operands ----
    {
      size_t base = ((size_t)(b0 + r32) * Ssz + t) * Dsz + c4;
      *(bf16x4*)&P.Sla[base] = *(const bf16x4*)&Ala[r32][c4];
      *(bf16x4*)&P.Slbp[base] = *(const bf16x4*)&Albp[r32][c4];
      *(bf16x4*)&P.Slbs[base] = *(const bf16x4*)&Albs[r32][c4];
      bf16x4 npv = *(const bf16x4*)&STG0[r32][c4];
      bf16x4 nsv = *(const bf16x4*)&STG1[r32][c4];
      *(bf16x4*)&P.proSt[base] = npv;
      *(bf16x4*)&P.skSt[base] = nsv;
      if (pf) {
        int lpN = iwN & 255, lsN = (iwN >> 8) & 255, naN = (iwN >> 16) & 1;
        *(bf16x4*)&Ala[r32][c4] = *(const bf16x4*)&STGa[r32][c4];
        *(bf16x4*)&Albp[r32][c4] = (lpN == t) ? npv : pPro;
        *(bf16x4*)&Albs[r32][c4] = (lsN == t) ? nsv : pSk;
        bf16x4 vx;
        for (int j = 0; j < 4; ++j) {
          float f = EMB ? (float)pNp[j] : pNpF[j];
          vx[j] = (bf16)(f + (naN ? aeH[j] : aeL[j]));
        }
        *(bf16x4*)&AnX[r32][c4] = vx;
#pragma unroll
        for (int r = 0; r < 4; ++r) {
          gpc[r] = gpn[r];
          gsc[r] = gsn[r];
        }
      }
    }
    __syncthreads();  // full sync: drains this step's stores (visibility for t+2 gathers)
  }
}

// ---------------- deferred head ----------------
struct HeadParams {
  const bf16 *Sla, *Slbp, *Slbs, *PWo1, *npe;
  const int *next_problem, *next_skill;
  const float *pro_embed, *skill_embed, *akt_pro_diff, *akt_pro_change;
  const float *b_o1, *W_o2, *b_o2;
  float *out;
};

template <int EMB>
__global__ void k_head(HeadParams P) {
  const int bt0 = blockIdx.x * 16;
  const int tid = threadIdx.x, lane = tid & 63, wv = tid >> 6;
  const int r16 = tid >> 4, c8 = (tid & 15) * 8;
  const int arow = lane & 15, apos = (lane >> 4) * 8;
  const int rb = (lane >> 4) * 4;
  const int nt0 = wv, nt1 = wv + 4;
  const int cAh = nt0 * 16 + (lane & 15), cBh = nt1 * 16 + (lane & 15);
  __shared__ __align__(16) bf16 Af[16][520];
  __shared__ float Hh[16][132];
  __shared__ float Hpart[16][16];
  __shared__ float w2s[128];
  if (tid < 128) w2s[tid] = P.W_o2[tid];
  {
    int bt = bt0 + r16;
    *(bf16x8*)&Af[r16][c8] = *(const bf16x8*)&P.Sla[(size_t)bt * 128 + c8];
    *(bf16x8*)&Af[r16][128 + c8] = *(const bf16x8*)&P.Slbp[(size_t)bt * 128 + c8];
    *(bf16x8*)&Af[r16][256 + c8] = *(const bf16x8*)&P.Slbs[(size_t)bt * 128 + c8];
    if (EMB) {
      *(bf16x8*)&Af[r16][384 + c8] = *(const bf16x8*)&P.npe[(size_t)bt * 128 + c8];
    } else {
      int np = P.next_problem[bt], ns = P.next_skill[bt];
      float diff = P.akt_pro_diff[np];
      f32x4 p0 = *(const f32x4*)&P.pro_embed[(size_t)np * 128 + c8];
      f32x4 p1 = *(const f32x4*)&P.pro_embed[(size_t)np * 128 + c8 + 4];
      f32x4 s0 = *(const f32x4*)&P.skill_embed[(size_t)ns * 128 + c8];
      f32x4 s1 = *(const f32x4*)&P.skill_embed[(size_t)ns * 128 + c8 + 4];
      f32x4 c0 = *(const f32x4*)&P.akt_pro_change[(size_t)ns * 128 + c8];
      f32x4 c1 = *(const f32x4*)&P.akt_pro_change[(size_t)ns * 128 + c8 + 4];
      bf16x8 vn;
      for (int j = 0; j < 4; ++j) {
        vn[j] = (bf16)(p0[j] + s0[j] + diff * c0[j]);
        vn[j + 4] = (bf16)(p1[j] + s1[j] + diff * c1[j]);
      }
      *(bf16x8*)&Af[r16][384 + c8] = vn;
    }
  }
  __syncthreads();
  f32x4 h0{}, h1{};
#pragma unroll
  for (int ks = 0; ks < 16; ++ks) {
    bf16x8 a = *(const bf16x8*)&Af[arow][ks * 32 + apos];
    h0 = mfma16(a, ldfrag(P.PWo1, 16, nt0, ks, lane), h0);
    h1 = mfma16(a, ldfrag(P.PWo1, 16, nt1, ks, lane), h1);
  }
  const float bo1A = P.b_o1[cAh], bo1B = P.b_o1[cBh];
  for (int r = 0; r < 4; ++r) {
    Hh[rb + r][cAh] = fmaxf(h0[r] + bo1A, 0.f);
    Hh[rb + r][cBh] = fmaxf(h1[r] + bo1B, 0.f);
  }
  __syncthreads();
  {
    int row = tid >> 4, cg = tid & 15;
    float s = 0.f;
    for (int j = 0; j < 8; ++j) s += Hh[row][cg * 8 + j] * w2s[cg * 8 + j];
    Hpart[row][cg] = s;
  }
  __syncthreads();
  if (tid < 16) {
    float s = 0.f;
    for (int k = 0; k < 16; ++k) s += Hpart[tid][k];
    P.out[bt0 + tid] = fsig(s + P.b_o2[0]);
  }
}

extern "C" void kernel_launch(void* const* d_in, const int* in_sizes, int n_in,
                              void* d_out, int out_size, void* d_ws, size_t ws_size,
                              hipStream_t stream) {
  const int* next_problem = (const int*)d_in[3];
  const int* next_skill = (const int*)d_in[4];
  const int* next_ans = (const int*)d_in[5];
  const float* pro_embed = (const float*)d_in[6];
  const float* skill_embed = (const float*)d_in[7];
  const float* ans_embed = (const float*)d_in[8];
  const float* time_embed = (const float*)d_in[9];
  const float* ls_state = (const float*)d_in[10];
  const float* pro_state0 = (const float*)d_in[11];
  const float* skill_state0 = (const float*)d_in[12];
  const float* akt_pro_diff = (const float*)d_in[13];
  const float* akt_pro_change = (const float*)d_in[14];
  const float* W_pf = (const float*)d_in[15];
  const float* b_pf = (const float*)d_in[16];
  const float* W_sf = (const float*)d_in[17];
  const float* b_sf = (const float*)d_in[18];
  const float* W_af = (const float*)d_in[19];
  const float* b_af = (const float*)d_in[20];
  const float* W_ps = (const float*)d_in[21];
  const float* b_ps = (const float*)d_in[22];
  const float* W_ss = (const float*)d_in[23];
  const float* b_ss = (const float*)d_in[24];
  const float* W_as = (const float*)d_in[25];
  const float* b_as = (const float*)d_in[26];
  const float* W_o1 = (const float*)d_in[27];
  const float* b_o1 = (const float*)d_in[28];
  const float* W_o2 = (const float*)d_in[29];
  const float* b_o2 = (const float*)d_in[30];

  char* ws = (char*)d_ws;
  size_t off = 0;
  auto alloc = [&](size_t bytes) -> void* {
    void* p = ws + off;
    off += bytes;
    off = (off + 255) & ~(size_t)255;
    return p;
  };
  bf16* proSt = (bf16*)alloc((size_t)Bsz * Ssz * Dsz * 2);
  bf16* skSt = (bf16*)alloc((size_t)Bsz * Ssz * Dsz * 2);
  u32* idx = (u32*)alloc((size_t)BTot * 4);
  float* TGEp = (float*)alloc(200 * 128 * 4);
  float* TGEs = (float*)alloc(200 * 128 * 4);
  float* cAF = (float*)alloc(128 * 4);
  bf16* PWpf = (bf16*)alloc(128 * 128 * 2);
  bf16* PWsf = (bf16*)alloc(128 * 128 * 2);
  bf16* PWaf = (bf16*)alloc(128 * 128 * 2);
  bf16* PWps = (bf16*)alloc(256 * 128 * 2);
  bf16* PWss = (bf16*)alloc(256 * 128 * 2);
  bf16* PWas = (bf16*)alloc(256 * 128 * 2);
  bf16* PWo1 = (bf16*)alloc(512 * 128 * 2);
  bf16* Sla = (bf16*)alloc((size_t)BTot * Dsz * 2);
  bf16* Slbp = (bf16*)alloc((size_t)BTot * Dsz * 2);
  bf16* Slbs = (bf16*)alloc((size_t)BTot * Dsz * 2);
  size_t off_base = off;
  bf16* npe = (bf16*)alloc((size_t)BTot * Dsz * 2);
  size_t off_emb = off;

  bool emb = (off_emb <= ws_size);
  if (!emb && off_base > ws_size) {
    hipMemsetAsync(d_out, 0xFF, (size_t)out_size * 4, stream);
    return;
  }

  k_idx<<<Bsz, 256, 0, stream>>>(next_problem, next_skill, next_ans, idx);
  k_pack<<<8, 256, 0, stream>>>(W_pf, PWpf, 128);
  k_pack<<<8, 256, 0, stream>>>(W_sf, PWsf, 128);
  k_pack<<<8, 256, 0, stream>>>(W_af, PWaf, 128);
  k_pack<<<16, 256, 0, stream>>>(W_ps, PWps, 256);
  k_pack<<<16, 256, 0, stream>>>(W_ss, PWss, 256);
  k_pack<<<16, 256, 0, stream>>>(W_as, PWas, 256);
  k_pack<<<32, 256, 0, stream>>>(W_o1, PWo1, 512);
  k_tge<<<200, 128, 0, stream>>>(time_embed, W_pf, b_pf, TGEp);
  k_tge<<<200, 128, 0, stream>>>(time_embed, W_sf, b_sf, TGEs);
  k_tge<<<1, 128, 0, stream>>>(time_embed + 128, W_af, b_af, cAF);
  if (emb)
    k_embed<<<(BTot * 32 + 255) / 256, 256, 0, stream>>>(
        next_problem, next_skill, pro_embed, skill_embed, akt_pro_diff, akt_pro_change, npe);

  MainParams mp;
  mp.next_problem = next_problem; mp.next_skill = next_skill;
  mp.pro_embed = pro_embed; mp.skill_embed = skill_embed;
  mp.akt_pro_diff = akt_pro_diff; mp.akt_pro_change = akt_pro_change;
  mp.ans_embed = ans_embed;
  mp.ls_state = ls_state; mp.pro_state0 = pro_state0; mp.skill_state0 = skill_state0;
  mp.idx = idx; mp.npe = npe;
  mp.TGEp = TGEp; mp.TGEs = TGEs; mp.cAF = cAF;
  mp.PWpf = PWpf; mp.PWsf = PWsf; mp.PWaf = PWaf;
  mp.PWps = PWps; mp.PWss = PWss; mp.PWas = PWas;
  mp.b_ps = b_ps; mp.b_ss = b_ss; mp.b_as = b_as;
  mp.proSt = proSt; mp.skSt = skSt;
  mp.Sla = Sla; mp.Slbp = Slbp; mp.Slbs = Slbs;

  HeadParams hp;
  hp.Sla = Sla; hp.Slbp = Slbp; hp.Slbs = Slbs; hp.PWo1 = PWo1; hp.npe = npe;
  hp.next_problem = next_problem; hp.next_skill = next_skill;
  hp.pro_embed = pro_embed; hp.skill_embed = skill_embed;
  hp.akt_pro_diff = akt_pro_diff; hp.akt_pro_change = akt_pro_change;
  hp.b_o1 = b_o1; hp.W_o2 = W_o2; hp.b_o2 = b_o2;
  hp.out = (float*)d_out;

  if (emb) {
    k_main<1><<<NBLK, 512, 0, stream>>>(mp);
    k_head<1><<<BTot / 16, 256, 0, stream>>>(hp);
  } else {
    k_main<0><<<NBLK, 512, 0, stream>>>(mp);
    k_head<0><<<BTot / 16, 256, 0, stream>>>(hp);
  }
}